// Round 7
// baseline (374.198 us; speedup 1.0000x reference)
//
#include <hip/hip_runtime.h>
#include <hip/hip_bf16.h>

typedef __attribute__((ext_vector_type(4))) float f32x4;
typedef __attribute__((ext_vector_type(8))) short bf16x8;

#define MFMA(a, b, c) __builtin_amdgcn_mfma_f32_16x16x32_bf16(a, b, c, 0, 0, 0)

__device__ __forceinline__ short f2bf(float f) {
    union { float f; unsigned u; } v; v.f = f;
    unsigned r = v.u + 0x7fffu + ((v.u >> 16) & 1u);
    return (short)(r >> 16);
}

__device__ __forceinline__ short f2bf_h(float f) {
    __hip_bfloat16 h = __float2bfloat16(f);
    return *reinterpret_cast<const short*>(&h);
}

__device__ __forceinline__ bf16x8 cvt8h(f32x4 a, f32x4 b) {
    bf16x8 r;
    #pragma unroll
    for (int i = 0; i < 4; ++i) {
        r[i]     = f2bf_h(a[i]);
        r[4 + i] = f2bf_h(b[i]);
    }
    return r;
}

// ws layout:
//   W_all [320][1024] bf16 @ short 0      (rows: seg*64+col; segs q,k1,v1,k2,v2)
//   weff  [1024][64]  bf16 @ short 327680
//   b_all [320]       f32  @ byte 786432
#define WS_WEFF   327680
#define WS_BALL_B 786432

__global__ __launch_bounds__(256) void prep_kernel(
        const float* __restrict__ lq_w, const float* __restrict__ lk1_w,
        const float* __restrict__ lk2_w, const float* __restrict__ lv1_w,
        const float* __restrict__ lv2_w, const float* __restrict__ lh_w,
        const float* __restrict__ lq_b, const float* __restrict__ lk1_b,
        const float* __restrict__ lk2_b, const float* __restrict__ lv1_b,
        const float* __restrict__ lv2_b,
        short* __restrict__ W_all, short* __restrict__ weff,
        float* __restrict__ b_all) {
    int t = blockIdx.x * 256 + threadIdx.x;
    if (t < 327680) {                       // W_all
        int row = t >> 10, col = t & 1023;
        int seg = row >> 6, sr = row & 63;
        const float* src = (seg == 0) ? lq_w : (seg == 1) ? lk1_w
                         : (seg == 2) ? lv1_w : (seg == 3) ? lk2_w : lv2_w;
        W_all[t] = f2bf(src[sr * 1024 + col]);
    } else if (t < 393216) {                // weff
        int i = t - 327680;
        int j = i >> 6, d = i & 63;
        float s = 0.f;
        #pragma unroll
        for (int h = 0; h < 16; ++h) s += lh_w[j * 1024 + h * 64 + d];
        weff[i] = f2bf(s);
    } else if (t < 393536) {                // b_all
        int i = t - 393216;
        int seg = i >> 6, si = i & 63;
        const float* src = (seg == 0) ? lq_b : (seg == 1) ? lk1_b
                         : (seg == 2) ? lv1_b : (seg == 3) ? lk2_b : lv2_b;
        b_all[i] = src[si];
    }
}

// Fused: block = 16 rows, 4 waves. K=1024 fully unrolled as 32 chunks of 32.
// NO LDS / NO barriers in the K loop: A fragments are per-lane 32B contiguous
// global loads (L1 dedups the 4-wave redundancy); W from L2. All loads are
// inline-asm (unsinkable), 2-deep register banks, one counted vmcnt(11) per
// chunk. Epilogue (gate + phase-2 GEMM) uses 24KB LDS once.
__global__ __launch_bounds__(256, 2) void fused_kernel(
        const float* __restrict__ Q, const float* __restrict__ K,
        const float* __restrict__ V, const short* __restrict__ W_all,
        const float* __restrict__ b_all, const short* __restrict__ weff,
        const float* __restrict__ lh_b, float* __restrict__ out) {
    __shared__ __align__(16) char lds[24576];
    const int tid  = threadIdx.x;
    const int wid  = tid >> 6;
    const int lane = tid & 63;
    const int lrow = lane & 15;
    const int lkg  = lane >> 4;
    const int RB   = blockIdx.x * 16;

    // A per-lane pointers: row RB+lrow, k base lkg*8 (fragment layout direct)
    const float* aq = Q + (size_t)(RB + lrow) * 1024 + lkg * 8;
    const float* ak = K + (size_t)(RB + lrow) * 1024 + lkg * 8;
    const float* av = V + (size_t)(RB + lrow) * 1024 + lkg * 8;

    // W fragment pointers (L2): row = seg*64 + wid*16 + lrow
    const short* w0 = W_all + (size_t)(0 * 64 + wid * 16 + lrow) * 1024 + lkg * 8;
    const short* w1 = W_all + (size_t)(1 * 64 + wid * 16 + lrow) * 1024 + lkg * 8;
    const short* w2 = W_all + (size_t)(2 * 64 + wid * 16 + lrow) * 1024 + lkg * 8;
    const short* w3 = W_all + (size_t)(3 * 64 + wid * 16 + lrow) * 1024 + lkg * 8;
    const short* w4 = W_all + (size_t)(4 * 64 + wid * 16 + lrow) * 1024 + lkg * 8;

    f32x4 acc[5];
    #pragma unroll
    for (int j = 0; j < 5; ++j) acc[j] = (f32x4){0.f, 0.f, 0.f, 0.f};

    f32x4  aA[2][6];   // [bank][input*2 + half]
    bf16x8 wB[2][5];   // [bank][output]

#define GLD4F(dst, p) \
    asm volatile("global_load_dwordx4 %0, %1, off" : "=&v"(dst) : "v"(p) : "memory")

#define ISSUE_A(c) {                                                   \
        GLD4F(aA[(c) & 1][0], aq + (c) * 32);                          \
        GLD4F(aA[(c) & 1][1], aq + (c) * 32 + 4);                      \
        GLD4F(aA[(c) & 1][2], ak + (c) * 32);                          \
        GLD4F(aA[(c) & 1][3], ak + (c) * 32 + 4);                      \
        GLD4F(aA[(c) & 1][4], av + (c) * 32);                          \
        GLD4F(aA[(c) & 1][5], av + (c) * 32 + 4);                      \
    }
#define ISSUE_W(c) {                                                   \
        GLD4F(wB[(c) & 1][0], w0 + (c) * 32);                          \
        GLD4F(wB[(c) & 1][1], w1 + (c) * 32);                          \
        GLD4F(wB[(c) & 1][2], w2 + (c) * 32);                          \
        GLD4F(wB[(c) & 1][3], w3 + (c) * 32);                          \
        GLD4F(wB[(c) & 1][4], w4 + (c) * 32);                          \
    }
#define COMPUTE(c) {                                                   \
        const bf16x8 fq = cvt8h(aA[(c) & 1][0], aA[(c) & 1][1]);       \
        const bf16x8 fk = cvt8h(aA[(c) & 1][2], aA[(c) & 1][3]);       \
        const bf16x8 fv = cvt8h(aA[(c) & 1][4], aA[(c) & 1][5]);       \
        acc[0] = MFMA(fq, wB[(c) & 1][0], acc[0]);                     \
        acc[1] = MFMA(fk, wB[(c) & 1][1], acc[1]);                     \
        acc[2] = MFMA(fk, wB[(c) & 1][2], acc[2]);                     \
        acc[3] = MFMA(fv, wB[(c) & 1][3], acc[3]);                     \
        acc[4] = MFMA(fv, wB[(c) & 1][4], acc[4]);                     \
    }

    // prologue: A(0),W(0),A(1),W(1) -> 22 outstanding
    ISSUE_A(0) ISSUE_W(0) ISSUE_A(1) ISSUE_W(1)

    // steady state: wait vmcnt(11) drains A(c),W(c); compute; issue c+2
    #pragma unroll
    for (int c = 0; c < 30; ++c) {
        asm volatile("s_waitcnt vmcnt(11)" ::: "memory");
        __builtin_amdgcn_sched_barrier(0);
        COMPUTE(c)
        ISSUE_A(c + 2)
        ISSUE_W(c + 2)
    }
    asm volatile("s_waitcnt vmcnt(11)" ::: "memory");   // drains A(30),W(30)
    __builtin_amdgcn_sched_barrier(0);
    COMPUTE(30)
    asm volatile("s_waitcnt vmcnt(0)" ::: "memory");    // drains A(31),W(31)
    __builtin_amdgcn_sched_barrier(0);
    COMPUTE(31)

#undef COMPUTE
#undef ISSUE_W
#undef ISSUE_A
#undef GLD4F

    __syncthreads();   // epilogue LDS exchange starts here

    // ---- gate epilogue: acc+bias -> epi f32 [16][324] ----
    float* epi = (float*)lds;
    #pragma unroll
    for (int j = 0; j < 5; ++j) {
        const int colj = j * 64 + wid * 16 + lrow;
        const float bb = b_all[colj];
        #pragma unroll
        for (int i = 0; i < 4; ++i)
            epi[(lkg * 4 + i) * 324 + colj] = acc[j][i] + bb;
    }
    __syncthreads();

    // gate: row r = lrow; partial over lkg (16 q-dims each); reduce xor 16,32
    const int r = lrow;
    const float* er = epi + r * 324;
    float p1 = 0.f, p2 = 0.f;
    #pragma unroll
    for (int jj = 0; jj < 16; ++jj) {
        const float qv = er[lkg * 16 + jj];
        p1 += qv * er[64  + lkg * 16 + jj];    // q . k1
        p2 += qv * er[192 + lkg * 16 + jj];    // q . k2
    }
    p1 += __shfl_xor(p1, 16, 64); p1 += __shfl_xor(p1, 32, 64);
    p2 += __shfl_xor(p2, 16, 64); p2 += __shfl_xor(p2, 32, 64);
    const float mx = fmaxf(p1, p2);
    const float e1 = __expf(p1 - mx);
    const float e2 = __expf(p2 - mx);
    const float inv = 1.f / (e1 + e2);
    const float g1 = e1 * inv, g2 = e2 * inv;

    short* head_s = (short*)(lds + 21504);  // [16][72] bf16 (above epi's 20.7KB)
    const int cb = wid * 16 + lkg * 4;
    #pragma unroll
    for (int j2 = 0; j2 < 4; ++j2) {
        const float h = g1 * er[128 + cb + j2] + g2 * er[256 + cb + j2];
        head_s[r * 72 + cb + j2] = f2bf_h(h);
    }
    __syncthreads();

    // ---- phase 2: out[16 x 1024] = head @ W_eff^T + lh_b; wave = 256 cols ----
    const bf16x8 ha0 = *(const bf16x8*)(head_s + lrow * 72 + lkg * 8);
    const bf16x8 ha1 = *(const bf16x8*)(head_s + lrow * 72 + 32 + lkg * 8);
    const int cgbase = wid * 256;
    #pragma unroll 4
    for (int jt = 0; jt < 16; ++jt) {
        const int col = cgbase + jt * 16 + lrow;
        const float bb = lh_b[col];
        f32x4 a = {bb, bb, bb, bb};
        const short* wp = weff + col * 64 + lkg * 8;
        a = MFMA(ha0, *(const bf16x8*)(wp), a);
        a = MFMA(ha1, *(const bf16x8*)(wp + 32), a);
        #pragma unroll
        for (int i = 0; i < 4; ++i)
            out[(size_t)(RB + lkg * 4 + i) * 1024 + col] = a[i];
    }
}

extern "C" void kernel_launch(void* const* d_in, const int* in_sizes, int n_in,
                              void* d_out, int out_size, void* d_ws, size_t ws_size,
                              hipStream_t stream) {
    const float* Q     = (const float*)d_in[0];
    const float* K     = (const float*)d_in[1];
    const float* V     = (const float*)d_in[2];
    const float* lq_w  = (const float*)d_in[3];
    const float* lq_b  = (const float*)d_in[4];
    const float* lk1_w = (const float*)d_in[5];
    const float* lk1_b = (const float*)d_in[6];
    const float* lk2_w = (const float*)d_in[7];
    const float* lk2_b = (const float*)d_in[8];
    const float* lv1_w = (const float*)d_in[9];
    const float* lv1_b = (const float*)d_in[10];
    const float* lv2_w = (const float*)d_in[11];
    const float* lv2_b = (const float*)d_in[12];
    const float* lh_w  = (const float*)d_in[13];
    const float* lh_b  = (const float*)d_in[14];
    float* out = (float*)d_out;

    short* W_all = (short*)d_ws;
    short* weff  = W_all + WS_WEFF;
    float* b_all = (float*)((char*)d_ws + WS_BALL_B);

    prep_kernel<<<1538, 256, 0, stream>>>(lq_w, lk1_w, lk2_w, lv1_w, lv2_w, lh_w,
                                          lq_b, lk1_b, lk2_b, lv1_b, lv2_b,
                                          W_all, weff, b_all);
    fused_kernel<<<2048, 256, 0, stream>>>(Q, K, V, W_all, b_all, weff, lh_b, out);
}

// Round 8
// 139.988 us; speedup vs baseline: 2.6731x; 2.6731x over previous
//
#include <hip/hip_runtime.h>
#include <hip/hip_bf16.h>

typedef __attribute__((ext_vector_type(4))) float f32x4;
typedef __attribute__((ext_vector_type(8))) short bf16x8;

#define MFMA(a, b, c) __builtin_amdgcn_mfma_f32_16x16x32_bf16(a, b, c, 0, 0, 0)

__device__ __forceinline__ short f2bf(float f) {
    union { float f; unsigned u; } v; v.f = f;
    unsigned r = v.u + 0x7fffu + ((v.u >> 16) & 1u);
    return (short)(r >> 16);
}

__device__ __forceinline__ short f2bf_h(float f) {
    __hip_bfloat16 h = __float2bfloat16(f);
    return *reinterpret_cast<const short*>(&h);
}

__device__ __forceinline__ bf16x8 cvt8h(f32x4 a, f32x4 b) {
    bf16x8 r;
    #pragma unroll
    for (int i = 0; i < 4; ++i) {
        r[i]     = f2bf_h(a[i]);
        r[4 + i] = f2bf_h(b[i]);
    }
    return r;
}

__device__ __forceinline__ void gll16(const void* g, const void* l) {
    __builtin_amdgcn_global_load_lds(
        (const __attribute__((address_space(1))) void*)g,
        (__attribute__((address_space(3))) void*)l, 16, 0, 0);
}

// ws layout:
//   W_frag [32 chunks][20 tiles][64 lanes] bf16x8 @ short 0   (327680 shorts)
//     tile = j*4 + wid (j=seg 0..4: q,k1,v1,k2,v2); lane=(lkg<<4)|lrow holds
//     W[j*64 + wid*16 + lrow][c*32 + lkg*8 .. +8]  -> wave load = 1KB dense
//   weff  [1024][64] bf16 @ short 327680
//   b_all [320]      f32  @ byte 786432
#define WS_WEFF   327680
#define WS_BALL_B 786432

__global__ __launch_bounds__(256) void prep_kernel(
        const float* __restrict__ lq_w, const float* __restrict__ lk1_w,
        const float* __restrict__ lk2_w, const float* __restrict__ lv1_w,
        const float* __restrict__ lv2_w, const float* __restrict__ lh_w,
        const float* __restrict__ lq_b, const float* __restrict__ lk1_b,
        const float* __restrict__ lk2_b, const float* __restrict__ lv1_b,
        const float* __restrict__ lv2_b,
        short* __restrict__ W_frag, short* __restrict__ weff,
        float* __restrict__ b_all) {
    int t = blockIdx.x * 256 + threadIdx.x;
    if (t < 327680) {                       // W_frag (fragment-order layout)
        const int e    = t & 7;             // element within bf16x8
        const int u16  = t >> 3;            // 16B cell index
        const int lane = u16 & 63;
        const int tl   = u16 >> 6;          // 0..639 = c*20 + tt
        const int c    = tl / 20;
        const int tt   = tl - c * 20;
        const int j    = tt >> 2;           // segment
        const int wd   = tt & 3;            // wave
        const int lrow = lane & 15;
        const int lkg  = lane >> 4;
        const float* src = (j == 0) ? lq_w : (j == 1) ? lk1_w
                         : (j == 2) ? lv1_w : (j == 3) ? lk2_w : lv2_w;
        W_frag[t] = f2bf(src[(wd * 16 + lrow) * 1024 + c * 32 + lkg * 8 + e]);
    } else if (t < 393216) {                // weff
        int i = t - 327680;
        int jj = i >> 6, d = i & 63;
        float s = 0.f;
        #pragma unroll
        for (int h = 0; h < 16; ++h) s += lh_w[jj * 1024 + h * 64 + d];
        weff[i] = f2bf(s);
    } else if (t < 393536) {                // b_all
        int i = t - 393216;
        int seg = i >> 6, si = i & 63;
        const float* src = (seg == 0) ? lq_b : (seg == 1) ? lk1_b
                         : (seg == 2) ? lv1_b : (seg == 3) ? lk2_b : lv2_b;
        b_all[i] = src[si];
    }
}

// Fused: block = 32 rows, 4 waves, K=1024 in 32 bodies of 32.
// A (Q/K/V f32): gll into 4-deep LDS ring (A(c+3) issued at body c — full HBM
// latency cover). W: fragment-order, 1KB-dense inline-asm loads into 2
// rotating reg banks (W(c+2) at body c). Per-wave FIFO waits: body =
// [3 gll A(c+3)] vmcnt(11) [compute] [5 W(c+2)] vmcnt(8) s_barrier.
__global__ __launch_bounds__(256, 3) void fused_kernel(
        const float* __restrict__ Q, const float* __restrict__ K,
        const float* __restrict__ V, const short* __restrict__ W_frag,
        const float* __restrict__ b_all, const short* __restrict__ weff,
        const float* __restrict__ lh_b, float* __restrict__ out) {
    __shared__ __align__(16) char lds[49152];   // 4 x 12KB A ring; epi reuse
    const int tid  = threadIdx.x;
    const int wid  = tid >> 6;
    const int lane = tid & 63;
    const int lrow = lane & 15;
    const int lkg  = lane >> 4;
    const int RB   = blockIdx.x * 32;

    // A staging: 12 gll/body (1KB = 8 rows x 128B), 3/wave. Source XOR-swizzle
    // within the 8-cell row chunk; LDS dest linear [input][row][128B].
    const float* asrc[3];
    int adst[3];
    #pragma unroll
    for (int u = 0; u < 3; ++u) {
        const int i   = wid * 3 + u;        // 0..11
        const int inp = i >> 2;             // 0=Q 1=K 2=V
        const int rg  = i & 3;              // 8-row group
        const int row = rg * 8 + (lane >> 3);
        const int gc  = (lane & 7) ^ (row & 7);
        const float* base = (inp == 0) ? Q : (inp == 1) ? K : V;
        asrc[u] = base + (size_t)(RB + row) * 1024 + gc * 4;
        adst[u] = inp * 4096 + rg * 1024;
    }

    // W fragment pointers: tile (j*4+wid), this lane's 16B cell. Dense 1KB/wave.
    const short* wsrc[5];
    #pragma unroll
    for (int j = 0; j < 5; ++j)
        wsrc[j] = W_frag + (size_t)((j * 4 + wid) * 64 + lane) * 8;

    f32x4 acc[2][5];
    #pragma unroll
    for (int rt = 0; rt < 2; ++rt)
        #pragma unroll
        for (int j = 0; j < 5; ++j) acc[rt][j] = (f32x4){0.f, 0.f, 0.f, 0.f};

    bf16x8 wA[5], wB[5];
    const int r7 = lrow & 7;
    const int c0 = ((lkg * 2)     ^ r7) << 4;
    const int c1 = ((lkg * 2 + 1) ^ r7) << 4;

#define GLD4(dst, p) \
    asm volatile("global_load_dwordx4 %0, %1, off" : "=&v"(dst) : "v"(p) : "memory")

    // ---- prologue: FIFO = A0(3), A1(3), W0(5), A2(3), W1(5) = 19 ----
    #pragma unroll
    for (int u = 0; u < 3; ++u) gll16(asrc[u], lds + adst[u]);
    #pragma unroll
    for (int u = 0; u < 3; ++u) gll16(asrc[u] + 32, lds + 12288 + adst[u]);
    #pragma unroll
    for (int j = 0; j < 5; ++j) GLD4(wA[j], wsrc[j]);
    #pragma unroll
    for (int u = 0; u < 3; ++u) gll16(asrc[u] + 64, lds + 24576 + adst[u]);
    #pragma unroll
    for (int j = 0; j < 5; ++j) GLD4(wB[j], wsrc[j] + 10240);
    asm volatile("s_waitcnt vmcnt(8)" ::: "memory");   // drains A0,A1,W0
    __builtin_amdgcn_sched_barrier(0);
    __builtin_amdgcn_s_barrier();
    __builtin_amdgcn_sched_barrier(0);

#define BODY(C, WB)                                                            \
    {                                                                          \
        /* (a) A(C+3) into ring slot (C+3)%4 */                                \
        const int kcA = ((C) + 3 <= 31) ? (C) + 3 : 31;                        \
        char* Db = lds + (((C) + 3) & 3) * 12288;                              \
        _Pragma("unroll")                                                      \
        for (int u = 0; u < 3; ++u) gll16(asrc[u] + kcA * 32, Db + adst[u]);   \
        /* (b) guard (no-op in steady state) */                                \
        asm volatile("s_waitcnt vmcnt(11)" ::: "memory");                      \
        __builtin_amdgcn_sched_barrier(0);                                     \
        /* compute slot C%4 with bank WB */                                    \
        const char* Ab = lds + ((C) & 3) * 12288;                              \
        bf16x8 fq[2], fk[2], fv[2];                                            \
        _Pragma("unroll")                                                      \
        for (int rt = 0; rt < 2; ++rt) {                                       \
            const int ro = (rt * 16 + lrow) * 128;                             \
            f32x4 q0 = *(const f32x4*)(Ab + ro + c0);                          \
            f32x4 q1 = *(const f32x4*)(Ab + ro + c1);                          \
            f32x4 k0 = *(const f32x4*)(Ab + 4096 + ro + c0);                   \
            f32x4 k1 = *(const f32x4*)(Ab + 4096 + ro + c1);                   \
            f32x4 v0 = *(const f32x4*)(Ab + 8192 + ro + c0);                   \
            f32x4 v1 = *(const f32x4*)(Ab + 8192 + ro + c1);                   \
            fq[rt] = cvt8h(q0, q1);                                            \
            fk[rt] = cvt8h(k0, k1);                                            \
            fv[rt] = cvt8h(v0, v1);                                            \
        }                                                                      \
        _Pragma("unroll")                                                      \
        for (int rt = 0; rt < 2; ++rt) {                                       \
            acc[rt][0] = MFMA(fq[rt], WB[0], acc[rt][0]);                      \
            acc[rt][1] = MFMA(fk[rt], WB[1], acc[rt][1]);                      \
            acc[rt][2] = MFMA(fk[rt], WB[2], acc[rt][2]);                      \
            acc[rt][3] = MFMA(fv[rt], WB[3], acc[rt][3]);                      \
            acc[rt][4] = MFMA(fv[rt], WB[4], acc[rt][4]);                      \
        }                                                                      \
        /* (c) W(C+2) into this bank (just consumed) */                        \
        const int kcW = ((C) + 2 <= 31) ? (C) + 2 : 31;                        \
        _Pragma("unroll")                                                      \
        for (int j = 0; j < 5; ++j)                                            \
            GLD4(WB[j], wsrc[j] + kcW * 10240);                                \
        /* (d) drain A(C+1) (next body's slot) + W(C+1); barrier */            \
        __builtin_amdgcn_sched_barrier(0);                                     \
        asm volatile("s_waitcnt vmcnt(8)" ::: "memory");                       \
        __builtin_amdgcn_sched_barrier(0);                                     \
        __builtin_amdgcn_s_barrier();                                          \
        __builtin_amdgcn_sched_barrier(0);                                     \
    }

    #pragma unroll 1
    for (int cc = 0; cc < 32; cc += 2) {
        BODY(cc, wA)
        BODY(cc + 1, wB)
    }
#undef BODY
#undef GLD4

    // drain tail junk (slots 1,2 — dead), then reuse LDS
    asm volatile("s_waitcnt vmcnt(0)" ::: "memory");
    __builtin_amdgcn_sched_barrier(0);
    __syncthreads();

    // ---- gate epilogue: acc+bias -> epi f32 [32][324] ----
    float* epi = (float*)lds;
    #pragma unroll
    for (int rt = 0; rt < 2; ++rt)
        #pragma unroll
        for (int j = 0; j < 5; ++j) {
            const int col = j * 64 + wid * 16 + lrow;
            const float bb = b_all[col];
            #pragma unroll
            for (int i = 0; i < 4; ++i)
                epi[(rt * 16 + lkg * 4 + i) * 324 + col] = acc[rt][j][i] + bb;
        }
    __syncthreads();

    // gate: row r = tid>>3, part p = tid&7 (8 lanes/row, in-wave reduce)
    const int r = tid >> 3;
    const int p = tid & 7;
    const float* er = epi + r * 324;
    float p1 = 0.f, p2 = 0.f;
    #pragma unroll
    for (int jj = 0; jj < 8; ++jj) {
        const float qv = er[p * 8 + jj];
        p1 += qv * er[64  + p * 8 + jj];    // q . k1
        p2 += qv * er[192 + p * 8 + jj];    // q . k2
    }
    p1 += __shfl_xor(p1, 1, 64); p1 += __shfl_xor(p1, 2, 64); p1 += __shfl_xor(p1, 4, 64);
    p2 += __shfl_xor(p2, 1, 64); p2 += __shfl_xor(p2, 2, 64); p2 += __shfl_xor(p2, 4, 64);
    const float mx = fmaxf(p1, p2);
    const float e1 = __expf(p1 - mx);
    const float e2 = __expf(p2 - mx);
    const float inv = 1.f / (e1 + e2);
    const float g1 = e1 * inv, g2 = e2 * inv;

    short* head_s = (short*)(lds + 41472);  // [32][72] bf16 (above epi)
    #pragma unroll
    for (int d = 0; d < 8; ++d) {
        const float h = g1 * er[128 + p * 8 + d] + g2 * er[256 + p * 8 + d];
        head_s[r * 72 + p * 8 + d] = f2bf_h(h);
    }
    __syncthreads();

    // ---- phase 2: out[32 x 1024] = head @ W_eff^T + lh_b; wave = 256 cols ----
    bf16x8 ha[2][2];
    #pragma unroll
    for (int rt = 0; rt < 2; ++rt) {
        ha[rt][0] = *(const bf16x8*)(head_s + (rt * 16 + lrow) * 72 + lkg * 8);
        ha[rt][1] = *(const bf16x8*)(head_s + (rt * 16 + lrow) * 72 + 32 + lkg * 8);
    }
    const int cgbase = wid * 256;
    #pragma unroll 4
    for (int jt = 0; jt < 16; ++jt) {
        const int col = cgbase + jt * 16 + lrow;
        const float bb = lh_b[col];
        const short* wp = weff + col * 64 + lkg * 8;
        const bf16x8 w0 = *(const bf16x8*)(wp);
        const bf16x8 w1 = *(const bf16x8*)(wp + 32);
        #pragma unroll
        for (int rt = 0; rt < 2; ++rt) {
            f32x4 a = {bb, bb, bb, bb};
            a = MFMA(ha[rt][0], w0, a);
            a = MFMA(ha[rt][1], w1, a);
            #pragma unroll
            for (int i = 0; i < 4; ++i)
                out[(size_t)(RB + rt * 16 + lkg * 4 + i) * 1024 + col] = a[i];
        }
    }
}

extern "C" void kernel_launch(void* const* d_in, const int* in_sizes, int n_in,
                              void* d_out, int out_size, void* d_ws, size_t ws_size,
                              hipStream_t stream) {
    const float* Q     = (const float*)d_in[0];
    const float* K     = (const float*)d_in[1];
    const float* V     = (const float*)d_in[2];
    const float* lq_w  = (const float*)d_in[3];
    const float* lq_b  = (const float*)d_in[4];
    const float* lk1_w = (const float*)d_in[5];
    const float* lk1_b = (const float*)d_in[6];
    const float* lk2_w = (const float*)d_in[7];
    const float* lk2_b = (const float*)d_in[8];
    const float* lv1_w = (const float*)d_in[9];
    const float* lv1_b = (const float*)d_in[10];
    const float* lv2_w = (const float*)d_in[11];
    const float* lv2_b = (const float*)d_in[12];
    const float* lh_w  = (const float*)d_in[13];
    const float* lh_b  = (const float*)d_in[14];
    float* out = (float*)d_out;

    short* W_frag = (short*)d_ws;
    short* weff   = W_frag + WS_WEFF;
    float* b_all  = (float*)((char*)d_ws + WS_BALL_B);

    prep_kernel<<<1538, 256, 0, stream>>>(lq_w, lk1_w, lk2_w, lv1_w, lv2_w, lh_w,
                                          lq_b, lk1_b, lk2_b, lv1_b, lv2_b,
                                          W_frag, weff, b_all);
    fused_kernel<<<1024, 256, 0, stream>>>(Q, K, V, W_frag, b_all, weff, lh_b, out);
}

// Round 11
// 137.336 us; speedup vs baseline: 2.7247x; 1.0193x over previous
//
#include <hip/hip_runtime.h>
#include <hip/hip_bf16.h>

typedef __attribute__((ext_vector_type(4))) float f32x4;
typedef __attribute__((ext_vector_type(8))) short bf16x8;

#define MFMA(a, b, c) __builtin_amdgcn_mfma_f32_16x16x32_bf16(a, b, c, 0, 0, 0)

__device__ __forceinline__ short f2bf(float f) {
    union { float f; unsigned u; } v; v.f = f;
    unsigned r = v.u + 0x7fffu + ((v.u >> 16) & 1u);
    return (short)(r >> 16);
}

__device__ __forceinline__ short f2bf_h(float f) {
    __hip_bfloat16 h = __float2bfloat16(f);
    return *reinterpret_cast<const short*>(&h);
}

__device__ __forceinline__ bf16x8 cvt8h(f32x4 a, f32x4 b) {
    bf16x8 r;
    #pragma unroll
    for (int i = 0; i < 4; ++i) {
        r[i]     = f2bf_h(a[i]);
        r[4 + i] = f2bf_h(b[i]);
    }
    return r;
}

__device__ __forceinline__ void gll16(const void* g, const void* l) {
    __builtin_amdgcn_global_load_lds(
        (const __attribute__((address_space(1))) void*)g,
        (__attribute__((address_space(3))) void*)l, 16, 0, 0);
}

// ws layout:
//   W_frag [32 chunks][20 tiles][64 lanes] bf16x8 @ short 0   (327680 shorts)
//     tile = j*4 + wid (j=seg 0..4: q,k1,v1,k2,v2); lane=(lkg<<4)|lrow holds
//     W[j*64 + wid*16 + lrow][c*32 + lkg*8 .. +8]  -> wave load = 1KB dense
//   weff  [1024][64] bf16 @ short 327680
//   b_all [320]      f32  @ byte 786432
#define WS_WEFF   327680
#define WS_BALL_B 786432

__global__ __launch_bounds__(256) void prep_kernel(
        const float* __restrict__ lq_w, const float* __restrict__ lk1_w,
        const float* __restrict__ lk2_w, const float* __restrict__ lv1_w,
        const float* __restrict__ lv2_w, const float* __restrict__ lh_w,
        const float* __restrict__ lq_b, const float* __restrict__ lk1_b,
        const float* __restrict__ lk2_b, const float* __restrict__ lv1_b,
        const float* __restrict__ lv2_b,
        short* __restrict__ W_frag, short* __restrict__ weff,
        float* __restrict__ b_all) {
    int t = blockIdx.x * 256 + threadIdx.x;
    if (t < 327680) {                       // W_frag (fragment-order layout)
        const int e    = t & 7;             // element within bf16x8
        const int u16  = t >> 3;            // 16B cell index
        const int lane = u16 & 63;
        const int tl   = u16 >> 6;          // 0..639 = c*20 + tt
        const int c    = tl / 20;
        const int tt   = tl - c * 20;
        const int j    = tt >> 2;           // segment
        const int wd   = tt & 3;            // wave
        const int lrow = lane & 15;
        const int lkg  = lane >> 4;
        const float* src = (j == 0) ? lq_w : (j == 1) ? lk1_w
                         : (j == 2) ? lv1_w : (j == 3) ? lk2_w : lv2_w;
        W_frag[t] = f2bf(src[(wd * 16 + lrow) * 1024 + c * 32 + lkg * 8 + e]);
    } else if (t < 393216) {                // weff
        int i = t - 327680;
        int jj = i >> 6, d = i & 63;
        float s = 0.f;
        #pragma unroll
        for (int h = 0; h < 16; ++h) s += lh_w[jj * 1024 + h * 64 + d];
        weff[i] = f2bf(s);
    } else if (t < 393536) {                // b_all
        int i = t - 393216;
        int seg = i >> 6, si = i & 63;
        const float* src = (seg == 0) ? lq_b : (seg == 1) ? lk1_b
                         : (seg == 2) ? lv1_b : (seg == 3) ? lk2_b : lv2_b;
        b_all[i] = src[si];
    }
}

// Fused: block = 32 rows, 4 waves, K=1024 in 32 bodies of 32.
// R8 structure (ring-4 A via gll, 2 W reg banks, per-body barrier) with the
// intra-body issue order swapped to W-then-A and the end-of-body wait relaxed
// to vmcnt(11): the 8-oldest drained at end of body C are exactly
// {A(C+1)3, W(C+1)5} — what body C+1 needs. A flight ~2 bodies (was ~1.2).
// Register footprint identical to R8 (no 3rd bank -> no spill risk).
__global__ __launch_bounds__(256, 3) void fused_kernel(
        const float* __restrict__ Q, const float* __restrict__ K,
        const float* __restrict__ V, const short* __restrict__ W_frag,
        const float* __restrict__ b_all, const short* __restrict__ weff,
        const float* __restrict__ lh_b, float* __restrict__ out) {
    __shared__ __align__(16) char lds[49152];   // 4 x 12KB A ring; epi reuse
    const int tid  = threadIdx.x;
    const int wid  = tid >> 6;
    const int lane = tid & 63;
    const int lrow = lane & 15;
    const int lkg  = lane >> 4;
    const int RB   = blockIdx.x * 32;

    // A staging: 12 gll/body (1KB = 8 rows x 128B), 3/wave. Source XOR-swizzle
    // within the 8-cell row chunk; LDS dest linear [input][row][128B].
    const float* asrc[3];
    int adst[3];
    #pragma unroll
    for (int u = 0; u < 3; ++u) {
        const int i   = wid * 3 + u;        // 0..11
        const int inp = i >> 2;             // 0=Q 1=K 2=V
        const int rg  = i & 3;              // 8-row group
        const int row = rg * 8 + (lane >> 3);
        const int gc  = (lane & 7) ^ (row & 7);
        const float* base = (inp == 0) ? Q : (inp == 1) ? K : V;
        asrc[u] = base + (size_t)(RB + row) * 1024 + gc * 4;
        adst[u] = inp * 4096 + rg * 1024;
    }

    // W fragment pointers: tile (j*4+wid), this lane's 16B cell. Dense 1KB/wave.
    const short* wsrc[5];
    #pragma unroll
    for (int j = 0; j < 5; ++j)
        wsrc[j] = W_frag + (size_t)((j * 4 + wid) * 64 + lane) * 8;

    f32x4 acc[2][5];
    #pragma unroll
    for (int rt = 0; rt < 2; ++rt)
        #pragma unroll
        for (int j = 0; j < 5; ++j) acc[rt][j] = (f32x4){0.f, 0.f, 0.f, 0.f};

    bf16x8 wE[5], wO[5];                    // 2 W reg banks (even/odd bodies)
    const int r7 = lrow & 7;
    const int c0 = ((lkg * 2)     ^ r7) << 4;
    const int c1 = ((lkg * 2 + 1) ^ r7) << 4;

#define GLD4(dst, p) \
    asm volatile("global_load_dwordx4 %0, %1, off" : "=&v"(dst) : "v"(p) : "memory")

    // ---- prologue FIFO: A(0)3, W(0)5, A(1)3, W(1)5, A(2)3 = 19 ----
    #pragma unroll
    for (int u = 0; u < 3; ++u) gll16(asrc[u], lds + adst[u]);
    #pragma unroll
    for (int j = 0; j < 5; ++j) GLD4(wE[j], wsrc[j]);
    #pragma unroll
    for (int u = 0; u < 3; ++u) gll16(asrc[u] + 32, lds + 12288 + adst[u]);
    #pragma unroll
    for (int j = 0; j < 5; ++j) GLD4(wO[j], wsrc[j] + 10240);
    #pragma unroll
    for (int u = 0; u < 3; ++u) gll16(asrc[u] + 64, lds + 24576 + adst[u]);
    asm volatile("s_waitcnt vmcnt(11)" ::: "memory");  // drains A(0)3+W(0)5
    __builtin_amdgcn_sched_barrier(0);
    __builtin_amdgcn_s_barrier();
    __builtin_amdgcn_sched_barrier(0);

    // Body C: entry remaining = [A(C+1)3, W(C+1)5, A(C+2)3].
    // compute(slot C&3, bank WB) -> W(C+2)->WB -> A(C+3)->slot (C+3)&3
    // -> vmcnt(11) (drains exactly A(C+1)+W(C+1)) -> barrier.
#define BODY(C, WB)                                                            \
    {                                                                          \
        const char* Ab = lds + ((C) & 3) * 12288;                              \
        bf16x8 fq[2], fk[2], fv[2];                                            \
        _Pragma("unroll")                                                      \
        for (int rt = 0; rt < 2; ++rt) {                                       \
            const int ro = (rt * 16 + lrow) * 128;                             \
            f32x4 q0 = *(const f32x4*)(Ab + ro + c0);                          \
            f32x4 q1 = *(const f32x4*)(Ab + ro + c1);                          \
            f32x4 k0 = *(const f32x4*)(Ab + 4096 + ro + c0);                   \
            f32x4 k1 = *(const f32x4*)(Ab + 4096 + ro + c1);                   \
            f32x4 v0 = *(const f32x4*)(Ab + 8192 + ro + c0);                   \
            f32x4 v1 = *(const f32x4*)(Ab + 8192 + ro + c1);                   \
            fq[rt] = cvt8h(q0, q1);                                            \
            fk[rt] = cvt8h(k0, k1);                                            \
            fv[rt] = cvt8h(v0, v1);                                            \
        }                                                                      \
        _Pragma("unroll")                                                      \
        for (int rt = 0; rt < 2; ++rt) {                                       \
            acc[rt][0] = MFMA(fq[rt], WB[0], acc[rt][0]);                      \
            acc[rt][1] = MFMA(fk[rt], WB[1], acc[rt][1]);                      \
            acc[rt][2] = MFMA(fk[rt], WB[2], acc[rt][2]);                      \
            acc[rt][3] = MFMA(fv[rt], WB[3], acc[rt][3]);                      \
            acc[rt][4] = MFMA(fv[rt], WB[4], acc[rt][4]);                      \
        }                                                                      \
        __builtin_amdgcn_sched_barrier(0);                                     \
        /* W(C+2) into WB (bank just consumed; write lands >=200cy later) */   \
        const int kw = ((C) + 2 <= 31) ? (C) + 2 : 31;                         \
        _Pragma("unroll")                                                      \
        for (int j = 0; j < 5; ++j) GLD4(WB[j], wsrc[j] + kw * 10240);         \
        /* A(C+3) into ring slot (C+3)&3 (consumed at body C-1; safe) */       \
        const int ka = ((C) + 3 <= 31) ? (C) + 3 : 31;                         \
        char* Db = lds + (((C) + 3) & 3) * 12288;                              \
        _Pragma("unroll")                                                      \
        for (int u = 0; u < 3; ++u) gll16(asrc[u] + ka * 32, Db + adst[u]);    \
        __builtin_amdgcn_sched_barrier(0);                                     \
        asm volatile("s_waitcnt vmcnt(11)" ::: "memory");                      \
        __builtin_amdgcn_sched_barrier(0);                                     \
        __builtin_amdgcn_s_barrier();                                          \
        __builtin_amdgcn_sched_barrier(0);                                     \
    }

    #pragma unroll 1
    for (int cc = 0; cc < 32; cc += 2) {
        BODY(cc, wE)
        BODY(cc + 1, wO)
    }
#undef BODY
#undef GLD4

    // drain tail junk (lands only in dead slots/banks), then reuse LDS
    asm volatile("s_waitcnt vmcnt(0)" ::: "memory");
    __builtin_amdgcn_sched_barrier(0);
    __syncthreads();

    // ---- gate epilogue: acc+bias -> epi f32 [32][324] (R8 verbatim) ----
    float* epi = (float*)lds;
    #pragma unroll
    for (int rt = 0; rt < 2; ++rt)
        #pragma unroll
        for (int j = 0; j < 5; ++j) {
            const int col = j * 64 + wid * 16 + lrow;
            const float bb = b_all[col];
            #pragma unroll
            for (int i = 0; i < 4; ++i)
                epi[(rt * 16 + lkg * 4 + i) * 324 + col] = acc[rt][j][i] + bb;
        }
    __syncthreads();

    // gate: row r = tid>>3, part p = tid&7 (8 lanes/row, in-wave reduce)
    const int r = tid >> 3;
    const int p = tid & 7;
    const float* er = epi + r * 324;
    float p1 = 0.f, p2 = 0.f;
    #pragma unroll
    for (int jj = 0; jj < 8; ++jj) {
        const float qv = er[p * 8 + jj];
        p1 += qv * er[64  + p * 8 + jj];    // q . k1
        p2 += qv * er[192 + p * 8 + jj];    // q . k2
    }
    p1 += __shfl_xor(p1, 1, 64); p1 += __shfl_xor(p1, 2, 64); p1 += __shfl_xor(p1, 4, 64);
    p2 += __shfl_xor(p2, 1, 64); p2 += __shfl_xor(p2, 2, 64); p2 += __shfl_xor(p2, 4, 64);
    const float mx = fmaxf(p1, p2);
    const float e1 = __expf(p1 - mx);
    const float e2 = __expf(p2 - mx);
    const float inv = 1.f / (e1 + e2);
    const float g1 = e1 * inv, g2 = e2 * inv;

    short* head_s = (short*)(lds + 41472);  // [32][72] bf16 (above epi)
    #pragma unroll
    for (int d = 0; d < 8; ++d) {
        const float h = g1 * er[128 + p * 8 + d] + g2 * er[256 + p * 8 + d];
        head_s[r * 72 + p * 8 + d] = f2bf_h(h);
    }
    __syncthreads();

    // ---- phase 2: out[32 x 1024] = head @ W_eff^T + lh_b; wave = 256 cols ----
    bf16x8 ha[2][2];
    #pragma unroll
    for (int rt = 0; rt < 2; ++rt) {
        ha[rt][0] = *(const bf16x8*)(head_s + (rt * 16 + lrow) * 72 + lkg * 8);
        ha[rt][1] = *(const bf16x8*)(head_s + (rt * 16 + lrow) * 72 + 32 + lkg * 8);
    }
    const int cgbase = wid * 256;
    #pragma unroll 4
    for (int jt = 0; jt < 16; ++jt) {
        const int col = cgbase + jt * 16 + lrow;
        const float bb = lh_b[col];
        const short* wp = weff + col * 64 + lkg * 8;
        const bf16x8 w0 = *(const bf16x8*)(wp);
        const bf16x8 w1 = *(const bf16x8*)(wp + 32);
        #pragma unroll
        for (int rt = 0; rt < 2; ++rt) {
            f32x4 a = {bb, bb, bb, bb};
            a = MFMA(ha[rt][0], w0, a);
            a = MFMA(ha[rt][1], w1, a);
            #pragma unroll
            for (int i = 0; i < 4; ++i)
                out[(size_t)(RB + rt * 16 + lkg * 4 + i) * 1024 + col] = a[i];
        }
    }
}

extern "C" void kernel_launch(void* const* d_in, const int* in_sizes, int n_in,
                              void* d_out, int out_size, void* d_ws, size_t ws_size,
                              hipStream_t stream) {
    const float* Q     = (const float*)d_in[0];
    const float* K     = (const float*)d_in[1];
    const float* V     = (const float*)d_in[2];
    const float* lq_w  = (const float*)d_in[3];
    const float* lq_b  = (const float*)d_in[4];
    const float* lk1_w = (const float*)d_in[5];
    const float* lk1_b = (const float*)d_in[6];
    const float* lk2_w = (const float*)d_in[7];
    const float* lk2_b = (const float*)d_in[8];
    const float* lv1_w = (const float*)d_in[9];
    const float* lv1_b = (const float*)d_in[10];
    const float* lv2_w = (const float*)d_in[11];
    const float* lv2_b = (const float*)d_in[12];
    const float* lh_w  = (const float*)d_in[13];
    const float* lh_b  = (const float*)d_in[14];
    float* out = (float*)d_out;

    short* W_frag = (short*)d_ws;
    short* weff   = W_frag + WS_WEFF;
    float* b_all  = (float*)((char*)d_ws + WS_BALL_B);

    prep_kernel<<<1538, 256, 0, stream>>>(lq_w, lk1_w, lk2_w, lv1_w, lv2_w, lh_w,
                                          lq_b, lk1_b, lk2_b, lv1_b, lv2_b,
                                          W_frag, weff, b_all);
    fused_kernel<<<1024, 256, 0, stream>>>(Q, K, V, W_frag, b_all, weff, lh_b, out);
}